// Round 11
// baseline (190.048 us; speedup 1.0000x reference)
//
#include <hip/hip_runtime.h>

typedef __bf16 bf16_t;
typedef bf16_t bf16x8 __attribute__((ext_vector_type(8)));
typedef float  f32x4  __attribute__((ext_vector_type(4)));
typedef float  f32x16 __attribute__((ext_vector_type(16)));
typedef unsigned int u32;
typedef u32    u32x4  __attribute__((ext_vector_type(4)));
typedef int    i32x2  __attribute__((ext_vector_type(2)));
typedef unsigned short u16;

#define B_SZ   4
#define N_SZ   4608
#define C_SZ   64
#define KVB    32
#define QROWS  32
#define NKVT   (N_SZ / KVB)     // 144
#define NQT    (N_SZ / QROWS)   // 144
#define WV     4                // waves per attn block
#define SPLIT  4                // block-level KV split
#define TPC    (NKVT / SPLIT)   // 36 tiles per chunk
#define TPW    (TPC / WV)       // 9 tiles per wave
#define NBLK   (B_SZ * NQT * SPLIT)   // 2304 partial blocks
#define RSC    1.2011224087864498f    // sqrt(1/ln2): Q,K scaled -> energy in base-2
#define THR    11.0f                  // defer-rescale threshold (base-2 units)

__device__ __forceinline__ f32x16 mfma32(bf16x8 a, bf16x8 b, f32x16 c) {
  return __builtin_amdgcn_mfma_f32_32x32x16_bf16(a, b, c, 0, 0, 0);
}
__device__ __forceinline__ u32 pk2(float a, float b) {
  u16 ua = __builtin_bit_cast(u16, (bf16_t)a);
  u16 ub = __builtin_bit_cast(u16, (bf16_t)b);
  return (u32)ua | ((u32)ub << 16);
}
// raw v_exp_f32 (base-2); inputs bounded above by THR, large-negative -> 0
__device__ __forceinline__ float ex2(float x) {
  float r;
  asm("v_exp_f32 %0, %1" : "=v"(r) : "v"(x));
  return r;
}
// v_permlane32_swap_b32 D,S: D.hi <-> S.lo.
// After: new_a = {a.lo | b.lo@hi-lanes}, new_b = {a.hi@lo-lanes | b.hi}.
// (r10 evidence: reversed operand order produced scrambled kv pairing ->
//  semantics confirmed as documented D.hi<->S.lo form.)
__device__ __forceinline__ void plswap(u32& a, u32& b) {
  i32x2 r = __builtin_amdgcn_permlane32_swap((int)a, (int)b, false, false);
  a = (u32)r.x; b = (u32)r.y;
}

// ---- pre-kernel: fp32 input -> khi/klo (bf16 hi/lo of RSC*v, row-major)
//                             -> vt (bf16 of v, transposed [b][c][n])
__global__ __launch_bounds__(256) void transform_k(
    const float* __restrict__ in, bf16_t* __restrict__ khi,
    bf16_t* __restrict__ klo, bf16_t* __restrict__ vt) {
  __shared__ float tile[64 * 65];
  const int bid = blockIdx.x;            // 288 blocks: (b, 64-row chunk)
  const int b  = bid / 72;
  const int n0 = (bid - b * 72) * 64;
  const int t  = threadIdx.x;
  {
    const int nl = t >> 2, c0 = (t & 3) * 16;
    const float* src = in + ((size_t)(b * N_SZ + n0 + nl)) * C_SZ + c0;
    float v[16];
    *(float4*)(v +  0) = *(const float4*)(src +  0);
    *(float4*)(v +  4) = *(const float4*)(src +  4);
    *(float4*)(v +  8) = *(const float4*)(src +  8);
    *(float4*)(v + 12) = *(const float4*)(src + 12);
    bf16x8 h8[2], l8[2];
#pragma unroll
    for (int i = 0; i < 16; ++i) {
      const float vs = RSC * v[i];
      bf16_t h = (bf16_t)vs;
      h8[i >> 3][i & 7] = h;
      l8[i >> 3][i & 7] = (bf16_t)(vs - (float)h);
      tile[nl * 65 + c0 + i] = v[i];     // vt stays UNSCALED
    }
    bf16_t* dh = khi + ((size_t)(b * N_SZ + n0 + nl)) * C_SZ + c0;
    bf16_t* dl = klo + ((size_t)(b * N_SZ + n0 + nl)) * C_SZ + c0;
    *(bf16x8*)(dh) = h8[0]; *(bf16x8*)(dh + 8) = h8[1];
    *(bf16x8*)(dl) = l8[0]; *(bf16x8*)(dl + 8) = l8[1];
  }
  __syncthreads();
  {
    const int c = t >> 2, m0 = (t & 3) * 16;
    bf16x8 o[2];
#pragma unroll
    for (int i = 0; i < 16; ++i)
      o[i >> 3][i & 7] = (bf16_t)tile[(m0 + i) * 65 + c];
    bf16_t* dst = vt + ((size_t)(b * C_SZ + c)) * N_SZ + n0 + m0;
    *(bf16x8*)(dst) = o[0]; *(bf16x8*)(dst + 8) = o[1];
  }
}

// ---- attention partials: 2304 blocks (b,qt,s) x 4 waves, 9 KV tiles/wave
// 32x32x16 MFMA path; softmax in-lane; permlane relayout; no LDS in hot loop.
__global__ __launch_bounds__(256, 4) void attn_part(
    const bf16_t* __restrict__ khi, const bf16_t* __restrict__ klo,
    const bf16_t* __restrict__ vt, float* __restrict__ wsO,
    float* __restrict__ wsML) {
  __shared__ float obuf[256 * 33];        // stride 33: conflict-free b32
  __shared__ float mlbuf[WV][2][32];

  const int bid0 = blockIdx.x;                      // 0..2303
  const int g8   = (bid0 & 7) * (NBLK / 8) + (bid0 >> 3);  // XCD-contiguous
  const int b    = g8 / (NQT * SPLIT);
  const int rem  = g8 - b * (NQT * SPLIT);
  const int s    = rem / NQT;
  const int qt   = rem - s * NQT;
  const int blk  = (b * NQT + qt) * SPLIT + s;      // partial index
  const int t  = threadIdx.x;
  const int w  = t >> 6, l = t & 63;
  const int q31 = l & 31, h = l >> 5;

  const bf16_t* kh_b = khi + (size_t)b * N_SZ * C_SZ;
  const bf16_t* kl_b = klo + (size_t)b * N_SZ * C_SZ;
  const bf16_t* vt_b = vt  + (size_t)b * C_SZ * N_SZ;

  // Q B-frags: B[k=ch][col=q31]; k-slot (h,i) <-> ch = 16*ks + 8*h + i
  bf16x8 qh[4], ql[4];
  {
    const bf16_t* qrh = kh_b + (size_t)(qt * QROWS + q31) * C_SZ + 8 * h;
    const bf16_t* qrl = kl_b + (size_t)(qt * QROWS + q31) * C_SZ + 8 * h;
#pragma unroll
    for (int ks = 0; ks < 4; ++ks) {
      qh[ks] = *(const bf16x8*)(qrh + 16 * ks);
      ql[ks] = *(const bf16x8*)(qrl + 16 * ks);
    }
  }

  f32x16 acc0 = {0,0,0,0,0,0,0,0,0,0,0,0,0,0,0,0};
  f32x16 acc1 = {0,0,0,0,0,0,0,0,0,0,0,0,0,0,0,0};
  float m_r = -3.0e38f, l_r = 0.f;

  for (int it = 0; it < TPW; ++it) {
    const int kv0 = (s * TPC + w + it * WV) * KVB;

    // K A-frags: A[row=kv0+q31][k=ch], same k-slot map as Q
    bf16x8 kah[4], kal[4];
    {
      const bf16_t* krh = kh_b + (size_t)(kv0 + q31) * C_SZ + 8 * h;
      const bf16_t* krl = kl_b + (size_t)(kv0 + q31) * C_SZ + 8 * h;
#pragma unroll
      for (int ks = 0; ks < 4; ++ks) {
        kah[ks] = *(const bf16x8*)(krh + 16 * ks);
        kal[ks] = *(const bf16x8*)(krl + 16 * ks);
      }
    }

    // S^T tile: lane holds S[kv=(r&3)+8*(r>>2)+4h][q=q31], base-2 energies
    f32x16 sv = {0,0,0,0,0,0,0,0,0,0,0,0,0,0,0,0};
#pragma unroll
    for (int ks = 0; ks < 4; ++ks) {
      sv = mfma32(kah[ks], qh[ks], sv);
      sv = mfma32(kah[ks], ql[ks], sv);
      sv = mfma32(kal[ks], qh[ks], sv);
    }

    // V^T A-frags (issue loads now; consumed after softmax); k-slot (h,i)<->kv=16ki+8h+i
    bf16x8 va[2][2];   // [c-block][kv-half]
#pragma unroll
    for (int cb = 0; cb < 2; ++cb)
#pragma unroll
      for (int ki = 0; ki < 2; ++ki)
        va[cb][ki] = *(const bf16x8*)(vt_b + (size_t)(cb * 32 + q31) * N_SZ
                                      + kv0 + 16 * ki + 8 * h);

    // row max: 15 in-lane + 1 cross-half shuffle
    float mx = sv[0];
#pragma unroll
    for (int r = 1; r < 16; ++r) mx = fmaxf(mx, sv[r]);
    mx = fmaxf(mx, __shfl_xor(mx, 32, 64));
    // T13 defer-rescale
    if (__any(mx > m_r + THR)) {
      const float mn = fmaxf(m_r, mx);
      const float sc = ex2(m_r - mn);
      m_r = mn;
      l_r *= sc;
#pragma unroll
      for (int r = 0; r < 16; ++r) { acc0[r] *= sc; acc1[r] *= sc; }
    }
    float rs = 0.f;
#pragma unroll
    for (int r = 0; r < 16; ++r) {
      const float e = ex2(sv[r] - m_r);
      sv[r] = e;
      rs += e;
    }
    rs += __shfl_xor(rs, 32, 64);
    l_r += rs;

    // pack P to bf16 pairs; permlane32_swap builds PV B-frags in-register.
    // pw[wd] holds kv pair (2wd,2wd+1)+4h-block per C/D row map.
    // Target kv0..15 frag: h=0 {pw0,pw1,partner.pw0,partner.pw1},
    //                      h=1 {partner.pw2,partner.pw3,pw2,pw3}
    //  -> plswap(pw0,pw2): pw0={pw0.lo|pw2.lo->hi}, pw2={pw0.hi->lo|pw2.hi}  (FIX: r10 had operands reversed)
    u32 pw[8];
#pragma unroll
    for (int wd = 0; wd < 8; ++wd) pw[wd] = pk2(sv[2 * wd], sv[2 * wd + 1]);
    plswap(pw[0], pw[2]); plswap(pw[1], pw[3]);   // kv 0..15 frag
    plswap(pw[4], pw[6]); plswap(pw[5], pw[7]);   // kv 16..31 frag
    const bf16x8 pb1 = __builtin_bit_cast(bf16x8, (u32x4){pw[0], pw[1], pw[2], pw[3]});
    const bf16x8 pb2 = __builtin_bit_cast(bf16x8, (u32x4){pw[4], pw[5], pw[6], pw[7]});

    // PV: O^T[c][q] accumulate
    acc0 = mfma32(va[0][0], pb1, acc0);
    acc0 = mfma32(va[0][1], pb2, acc0);
    acc1 = mfma32(va[1][0], pb1, acc1);
    acc1 = mfma32(va[1][1], pb2, acc1);
  }

  // ---- in-block merge of the 4 kv-split waves; write chunk partial to ws ----
  {
    float* ob = obuf + (size_t)(w * 64 + l) * 33;
#pragma unroll
    for (int r = 0; r < 16; ++r) ob[r] = acc0[r];
#pragma unroll
    for (int r = 0; r < 16; ++r) ob[16 + r] = acc1[r];
    if (l < 32) { mlbuf[w][0][l] = m_r; mlbuf[w][1][l] = l_r; }
  }
  __syncthreads();

  float* pO  = wsO  + (size_t)blk * (QROWS * C_SZ);
  float* pML = wsML + (size_t)blk * (QROWS * 2);
  {
    float mw[4], lw[4];
#pragma unroll
    for (int wp = 0; wp < 4; ++wp) {
      mw[wp] = mlbuf[wp][0][q31];
      lw[wp] = mlbuf[wp][1][q31];
    }
    const float ms = fmaxf(fmaxf(mw[0], mw[1]), fmaxf(mw[2], mw[3]));
    float ls = 0.f;
    f32x4 r0 = (f32x4){0.f, 0.f, 0.f, 0.f};
    f32x4 r1 = (f32x4){0.f, 0.f, 0.f, 0.f};
    const int ofs = (w >> 1) * 16 + 8 * (w & 1);   // wave w merges c in [16w,16w+16)
#pragma unroll
    for (int wp = 0; wp < 4; ++wp) {
      const float cf = ex2(mw[wp] - ms);
      ls += cf * lw[wp];
      const float* src = obuf + (size_t)(wp * 64 + l) * 33 + ofs;
#pragma unroll
      for (int i = 0; i < 4; ++i) r0[i] += cf * src[i];
#pragma unroll
      for (int i = 0; i < 4; ++i) r1[i] += cf * src[4 + i];
    }
    const int cb0 = 16 * w + 4 * h;                 // c = cb0+{0..3}, cb0+8+{0..3}
    *(f32x4*)&pO[q31 * C_SZ + cb0]     = r0;
    *(f32x4*)&pO[q31 * C_SZ + cb0 + 8] = r1;
    if (w == 0 && l < 32) {
      pML[l * 2 + 0] = ms;
      pML[l * 2 + 1] = ls;
    }
  }
}

// ---- combine: 576 blocks (b,qt); merge 4 chunk-partials, residual+gamma ----
__global__ __launch_bounds__(256) void combine_k(
    const float* __restrict__ in, const float* __restrict__ gamma_p,
    const float* __restrict__ wsO, const float* __restrict__ wsML,
    float* __restrict__ out) {
  const int bid = blockIdx.x;            // b*NQT + qt
  const int b   = bid / NQT;
  const int qt  = bid - b * NQT;
  const int t   = threadIdx.x;
  const int q   = t >> 3;                // 0..31
  const int c0  = (t & 7) * 8;           // 0..56
  const int blk0 = bid * SPLIT;

  float m[SPLIT], lv[SPLIT];
  f32x4 o0[SPLIT], o1[SPLIT];
#pragma unroll
  for (int s = 0; s < SPLIT; ++s) {
    const float* pML = wsML + (size_t)(blk0 + s) * (QROWS * 2);
    m[s]  = pML[q * 2 + 0];
    lv[s] = pML[q * 2 + 1];
    const float* pO = wsO + (size_t)(blk0 + s) * (QROWS * C_SZ) + q * C_SZ + c0;
    o0[s] = *(const f32x4*)(pO);
    o1[s] = *(const f32x4*)(pO + 4);
  }
  const float ms = fmaxf(fmaxf(m[0], m[1]), fmaxf(m[2], m[3]));
  float ls = 0.f;
  f32x4 a0 = (f32x4){0.f, 0.f, 0.f, 0.f};
  f32x4 a1 = (f32x4){0.f, 0.f, 0.f, 0.f};
#pragma unroll
  for (int s = 0; s < SPLIT; ++s) {
    const float cf = exp2f(m[s] - ms);
    ls += cf * lv[s];
    a0 += o0[s] * cf;
    a1 += o1[s] * cf;
  }
  const float sc = gamma_p[0] / ls;
  const int row = qt * QROWS + q;
  const size_t base = ((size_t)(b * N_SZ + row)) * C_SZ + c0;
  const float4 i0 = *(const float4*)(in + base);
  const float4 i1 = *(const float4*)(in + base + 4);
  float4 v0, v1;
  v0.x = a0[0] * sc + i0.x; v0.y = a0[1] * sc + i0.y;
  v0.z = a0[2] * sc + i0.z; v0.w = a0[3] * sc + i0.w;
  v1.x = a1[0] * sc + i1.x; v1.y = a1[1] * sc + i1.y;
  v1.z = a1[2] * sc + i1.z; v1.w = a1[3] * sc + i1.w;
  *(float4*)(out + base)     = v0;
  *(float4*)(out + base + 4) = v1;
}

extern "C" void kernel_launch(void* const* d_in, const int* in_sizes, int n_in,
                              void* d_out, int out_size, void* d_ws, size_t ws_size,
                              hipStream_t stream) {
  const float* in = (const float*)d_in[0];
  const float* gp = (const float*)d_in[1];
  float* op = (float*)d_out;
  const size_t plane = (size_t)B_SZ * N_SZ * C_SZ;   // elements
  bf16_t* khi = (bf16_t*)d_ws;
  bf16_t* klo = khi + plane;
  bf16_t* vt  = klo + plane;
  float*  wsO  = (float*)((char*)d_ws + 3 * plane * sizeof(bf16_t));
  float*  wsML = wsO + (size_t)NBLK * (QROWS * C_SZ);
  // total ws use: 7.08 MB + 18.9 MB + 0.59 MB = 26.5 MB (fit proven in r9)

  hipLaunchKernelGGL(transform_k, dim3(288), dim3(256), 0, stream, in, khi, klo, vt);
  hipLaunchKernelGGL(attn_part, dim3(NBLK), dim3(256), 0, stream,
                     khi, klo, vt, wsO, wsML);
  hipLaunchKernelGGL(combine_k, dim3(B_SZ * NQT), dim3(256), 0, stream,
                     in, gp, wsO, wsML, op);
}